// Round 7
// baseline (358.903 us; speedup 1.0000x reference)
//
#include <hip/hip_runtime.h>

#define NSHOTS 4
#define NT     512
#define NZ     256
#define NX     256
#define NRECS  128

static constexpr float DTf    = 0.001f;
static constexpr float INVDH2 = 1.0f / (10.0f * 10.0f);

#define KSTEPS 16                 // fused steps per phase
#define TILE   32                 // interior tile edge
#define SLAB   8                  // exact (owned) rows per wave
#define WPAIR  6                  // 12-row register window = 6 v2f pairs
#define NWAVES 8
#define BLOCK  512
#define NWG    (NSHOTS * 64)      // 256 WGs, one per CU (co-resident)
#define NPHASE (NT / KSTEPS)      // 32

typedef float v2f __attribute__((ext_vector_type(2)));
typedef unsigned long long ull;

// lane i <- lane i-1 (left x-neighbor); OOB lane 0 reads 0 (bound_ctrl=1)
__device__ __forceinline__ float nbr_left(float v) {
  return __int_as_float(__builtin_amdgcn_update_dpp(
      0, __float_as_int(v), 0x138 /*WAVE_SHR1*/, 0xf, 0xf, true));
}
// lane i <- lane i+1 (right x-neighbor); OOB lane 63 reads 0
__device__ __forceinline__ float nbr_right(float v) {
  return __int_as_float(__builtin_amdgcn_update_dpp(
      0, __float_as_int(v), 0x130 /*WAVE_SHL1*/, 0xf, 0xf, true));
}

// LLC-coherent (cross-XCD) 8B access: agent-scope relaxed -> sc0 sc1.
__device__ __forceinline__ ull pload(const ull* p) {
  return __hip_atomic_load(p, __ATOMIC_RELAXED, __HIP_MEMORY_SCOPE_AGENT);
}
__device__ __forceinline__ void pstore(ull* p, ull v) {
  __hip_atomic_store(p, v, __ATOMIC_RELAXED, __HIP_MEMORY_SCOPE_AGENT);
}

// pack (cur, prev) into one self-tagged 8B word: low 2 bits of prev's
// mantissa carry the phase tag (<= 3 ulp perturbation of halo prev only)
__device__ __forceinline__ ull pack_w(float cur, float prev, unsigned tg) {
  const unsigned hi = (__float_as_uint(prev) & ~3u) | tg;
  return ((ull)hi << 32) | (ull)__float_as_uint(cur);
}
__device__ __forceinline__ float w_cur(ull w) {
  return __uint_as_float((unsigned)w);
}
__device__ __forceinline__ float w_prev(ull w) {
  return __uint_as_float(((unsigned)(w >> 32)) & ~3u);
}
// per-buffer tag cycles 1,2,3 (phase q uses buffer q&1): never 0 (= memset)
__device__ __forceinline__ unsigned tag_of(int q) {
  return ((unsigned)(q >> 1) % 3u) + 1u;
}

__global__ __launch_bounds__(BLOCK, 2) void wave_pk(
    ull* __restrict__ gA, ull* __restrict__ gB,         // tagged (cur,prev) buffers
    const float* __restrict__ vp, const float* __restrict__ xwav,
    const int* __restrict__ src_z, const int* __restrict__ src_x,
    const int* __restrict__ rec_z, const int* __restrict__ rec_x,
    float* __restrict__ out)                            // [NSHOTS*NT*NRECS]
{
  const int bid  = blockIdx.x;
  const int s    = bid >> 6;
  const int tz   = (bid >> 3) & 7;
  const int tx   = bid & 7;
  const int tid  = threadIdx.x;
  const int w    = tid >> 6;
  const int lane = tid & 63;

  const int gz0 = tz * TILE - KSTEPS;   // WG ext origin (z), 64 ext rows
  const int gx0 = tx * TILE - KSTEPS;
  const int gx  = gx0 + lane;
  const int zb  = w * SLAB;             // my slab's ext-row base
  const bool xok = (unsigned)gx < (unsigned)NX;

  __shared__ float xchC[2][NWAVES][4][64];   // cur boundary rows (dbuf)
  __shared__ float xchP[NWAVES][2][64];      // prev boundary rows (EX0 only)
  __shared__ int   lzS[NRECS], lxS[NRECS];

  // slab row global offsets/validity (window rows 2..9)
  int offRow[SLAB];
  unsigned okMask = 0;
  #pragma unroll
  for (int k = 0; k < SLAB; ++k) {
    const int gz = gz0 + zb + k;
    const bool ok = xok && (unsigned)gz < (unsigned)NZ;
    offRow[k] = ok ? ((s * NZ + gz) * NX + gx) : 0;
    if (ok) okMask |= 1u << k;
  }

  // coefficients over the 12-row window; rows outside WG-ext or domain get
  // c2=0, d2=2 -> stay exactly 0 from 0 init (zero-pad semantics)
  v2f c22[WPAIR], d22[WPAIR], a2[WPAIR], b2[WPAIR];
  #pragma unroll
  for (int p = 0; p < WPAIR; ++p) {
    #pragma unroll
    for (int h = 0; h < 2; ++h) {
      const int e  = zb - 2 + 2 * p + h;          // ext row of window row
      const int gz = gz0 + e;
      const bool ok = ((unsigned)e < 64u) && xok && ((unsigned)gz < (unsigned)NZ);
      float v = ok ? vp[gz * NX + gx] : 0.0f;
      v *= DTf;
      const float c2 = v * v * INVDH2;
      if (h == 0) { c22[p].x = c2; d22[p].x = 2.0f - 4.0f * c2; }
      else        { c22[p].y = c2; d22[p].y = 2.0f - 4.0f * c2; }
    }
    a2[p] = (v2f)(0.0f); b2[p] = (v2f)(0.0f);
  }

  // interior (writeback) threads: slab in WG-interior, interior lane
  const bool wbT = (w >= 2 && w < 6) && (lane >= KSTEPS && lane < KSTEPS + TILE);

  // receiver table -> LDS, then per-thread ownership scan
  if (tid < NRECS) {
    lzS[tid] = rec_z[s * NRECS + tid] - tz * TILE;
    lxS[tid] = rec_x[s * NRECS + tid] - tx * TILE;
  }
  __syncthreads();
  unsigned e0 = 0, e1 = 0, rB0 = 0, rB1 = 0, rB2 = 0, rB3 = 0;
  if (wbT) {
    int cnt = 0;
    #pragma unroll 1
    for (int r = 0; r < NRECS; ++r) {
      const int er = lzS[r], ex = lxS[r];
      if ((unsigned)er < (unsigned)TILE && (unsigned)ex < (unsigned)TILE) {
        const int extz = er + KSTEPS;
        if ((extz >> 3) == w && ex + KSTEPS == lane) {
          const int wr = extz - zb + 2;           // window row, 2..9
          const unsigned e = 0x8000u | ((unsigned)wr << 8) | (unsigned)r;
          if (cnt == 0) e0 = e;
          else if (cnt == 1) e1 = e;
          else {
            if (r < 32)      rB0 |= 1u << r;
            else if (r < 64) rB1 |= 1u << (r - 32);
            else if (r < 96) rB2 |= 1u << (r - 64);
            else             rB3 |= 1u << (r - 96);
          }
          ++cnt;
        }
      }
    }
  }
  const bool hasOvf = (rB0 | rB1 | rB2 | rB3) != 0;

  // source: ext coords; inject anywhere in my window (redundant across
  // overlapping windows keeps halo evolution consistent)
  const int slz = src_z[s] - gz0;
  const int slx = src_x[s] - gx0;
  const int srcRow = slz - (zb - 2);              // window row of source
  const bool hasSrc = ((unsigned)slz < 64u) && ((unsigned)slx < 64u) &&
                      ((unsigned)srcRow < 12u);   // wave-uniform
  const bool srcLane = (slx == lane);

  float amp[KSTEPS];

  // select slab value at window row wr (2..9) without runtime indexing
  auto selSlab = [](const v2f (&n)[WPAIR], int wr) -> float {
    const int q = (wr >> 1) - 1;                  // 0..3 -> pairs 1..4
    const v2f pA = (q & 1) ? n[2] : n[1];
    const v2f pB = (q & 1) ? n[4] : n[3];
    const v2f pp = (q & 2) ? pB : pA;
    return (wr & 1) ? pp.y : pp.x;
  };

  // one step: pure registers + DPP (no LDS, no barrier)
  auto do_step = [&](v2f (&cur)[WPAIR], v2f (&nxt)[WPAIR], int tau, int t0) {
    #pragma unroll
    for (int p = 0; p < WPAIR; ++p) {
      const float cx = cur[p].x, cy = cur[p].y;
      const float upx = (p == 0)         ? 0.0f : cur[p - 1].y;
      const float dny = (p == WPAIR - 1) ? 0.0f : cur[p + 1].x;
      v2f ud, lr;
      ud.x = upx + cy;
      ud.y = cx + dny;
      lr.x = nbr_left(cx) + nbr_right(cx);
      lr.y = nbr_left(cy) + nbr_right(cy);
      const v2f sum = ud + lr;
      v2f t = __builtin_elementwise_fma(c22[p], sum, -nxt[p]);
      t = __builtin_elementwise_fma(d22[p], cur[p], t);
      nxt[p] = t;
    }
    if (hasSrc) {
      const float av = amp[tau];
      #pragma unroll
      for (int p = 0; p < WPAIR; ++p) {
        if (srcLane && srcRow == 2 * p)     nxt[p].x += av;
        if (srcLane && srcRow == 2 * p + 1) nxt[p].y += av;
      }
    }
    // receiver stores: owner thread has the value in registers
    const int t = t0 + tau;
    if (e0 & 0x8000u)
      out[(s * NT + t) * NRECS + (e0 & 127u)] = selSlab(nxt, (e0 >> 8) & 15);
    if (e1 & 0x8000u)
      out[(s * NT + t) * NRECS + (e1 & 127u)] = selSlab(nxt, (e1 >> 8) & 15);
    if (hasOvf) {                                  // >2 recs on one thread
      #pragma unroll
      for (int wd = 0; wd < 4; ++wd) {
        unsigned m = (wd == 0) ? rB0 : (wd == 1) ? rB1 : (wd == 2) ? rB2 : rB3;
        while (m) {
          const int b = __builtin_ctz(m); m &= m - 1;
          const int r = wd * 32 + b;
          const int wr = lzS[r] + KSTEPS - zb + 2;
          out[(s * NT + t) * NRECS + r] = selSlab(nxt, wr);
        }
      }
    }
  };

  // single-barrier, double-buffered window exchange (every 2 steps):
  // publish my slab's 2 boundary rows each side (cur), import neighbors'.
  // EX0 (phase start) also carries the boundary prev rows.
  auto exchange = [&](int buf, bool withPrev) {
    xchC[buf][w][0][lane] = a2[1].x;   // window row 2
    xchC[buf][w][1][lane] = a2[1].y;   // window row 3
    xchC[buf][w][2][lane] = a2[4].x;   // window row 8
    xchC[buf][w][3][lane] = a2[4].y;   // window row 9
    if (withPrev) {
      xchP[w][0][lane] = b2[1].x;      // prev row 2
      xchP[w][1][lane] = b2[4].y;      // prev row 9
    }
    __syncthreads();
    if (w > 0) {
      a2[0].x = xchC[buf][w - 1][2][lane];         // row 0 <- w-1 row 8
      a2[0].y = xchC[buf][w - 1][3][lane];         // row 1 <- w-1 row 9
      if (withPrev) b2[0].y = xchP[w - 1][1][lane];// prev row 1
    }
    if (w < NWAVES - 1) {
      a2[5].x = xchC[buf][w + 1][0][lane];         // row 10 <- w+1 row 2
      a2[5].y = xchC[buf][w + 1][1][lane];         // row 11 <- w+1 row 3
      if (withPrev) b2[5].x = xchP[w + 1][0][lane];// prev row 10
    }
    // WAR across EXs: buf alternates; re-publish of same buf is 2 EXs
    // (one barrier) later -> safe with the single barrier above.
  };

  #pragma unroll 1
  for (int ph = 0; ph < NPHASE; ++ph) {
    const int t0 = ph * KSTEPS;

    if (hasSrc) {     // only source-carrying waves need the wavelet
      const float4* xw4 = (const float4*)(xwav + s * NT + t0);
      #pragma unroll
      for (int q = 0; q < KSTEPS / 4; ++q) {
        const float4 v = xw4[q];
        amp[4 * q + 0] = (v.x * DTf) * DTf;
        amp[4 * q + 1] = (v.y * DTf) * DTf;
        amp[4 * q + 2] = (v.z * DTf) * DTf;
        amp[4 * q + 3] = (v.w * DTf) * DTf;
      }
    }

    if (ph > 0 && !wbT) {
      // fused poll+reload on self-tagged data words (R6-proven protocol):
      // tag match certifies producer's writeback AND (program order +
      // barriers) its prior reload -> covers data-dep and anti-dep.
      const ull* gR = (ph & 1) ? gA : gB;
      const unsigned tg = tag_of(ph - 1);
      ull vw[SLAB];
      unsigned need = okMask;
      while (need) {
        ull t[SLAB];
        #pragma unroll
        for (int i = 0; i < SLAB; ++i)
          if (need & (1u << i)) t[i] = pload(gR + offRow[i]);
        #pragma unroll
        for (int i = 0; i < SLAB; ++i)
          if ((need & (1u << i)) && (((unsigned)(t[i] >> 32)) & 3u) == tg) {
            vw[i] = t[i];
            need &= ~(1u << i);
          }
        if (need) __builtin_amdgcn_s_sleep(1);
      }
      #pragma unroll
      for (int k = 0; k < SLAB; ++k) {
        const bool ok = (okMask >> k) & 1;
        const float cv = ok ? w_cur(vw[k])  : 0.0f;
        const float pv = ok ? w_prev(vw[k]) : 0.0f;
        const int p = 1 + (k >> 1);
        if (k & 1) { a2[p].y = cv; b2[p].y = pv; }
        else       { a2[p].x = cv; b2[p].x = pv; }
      }
    }

    #pragma unroll
    for (int blk = 0; blk < KSTEPS / 2; ++blk) {
      exchange(blk & 1, blk == 0);
      do_step(a2, b2, 2 * blk,     t0);
      do_step(b2, a2, 2 * blk + 1, t0);
    }
    // after 16 steps: a2 = p(t0+16) slab-exact, b2 = p(t0+15) rows 1..10

    if (ph != NPHASE - 1 && wbT) {
      // tagged writeback IS the handshake signal (no drain, no flag)
      ull* gW = (ph & 1) ? gB : gA;
      const unsigned tgw = tag_of(ph);
      #pragma unroll
      for (int k = 0; k < SLAB; ++k) {
        const int p = 1 + (k >> 1);
        const float cv = (k & 1) ? a2[p].y : a2[p].x;
        const float pv = (k & 1) ? b2[p].y : b2[p].x;
        pstore(gW + offRow[k], pack_w(cv, pv, tgw));
      }
    }
  }
}

extern "C" void kernel_launch(void* const* d_in, const int* in_sizes, int n_in,
                              void* d_out, int out_size, void* d_ws, size_t ws_size,
                              hipStream_t stream) {
  const float* x     = (const float*)d_in[0];
  const float* vp    = (const float*)d_in[1];
  const int*   src_z = (const int*)d_in[2];
  const int*   src_x = (const int*)d_in[3];
  const int*   rec_z = (const int*)d_in[4];
  const int*   rec_x = (const int*)d_in[5];
  float* out = (float*)d_out;

  const size_t F = (size_t)NSHOTS * NZ * NX;
  ull* gA = (ull*)d_ws;                 // tagged (cur,prev), F words
  ull* gB = gA + F;                     // F words

  // zero both buffers: tag bits 0 never match any valid tag (1..3)
  hipMemsetAsync(gA, 0, 2 * F * sizeof(ull), stream);

  wave_pk<<<dim3(NWG), dim3(BLOCK), 0, stream>>>(
      gA, gB, vp, x, src_z, src_x, rec_z, rec_x, out);
}

// Round 8
// 316.456 us; speedup vs baseline: 1.1341x; 1.1341x over previous
//
#include <hip/hip_runtime.h>

#define NSHOTS 4
#define NT     512
#define NZ     256
#define NX     256
#define NRECS  128

static constexpr float DTf    = 0.001f;
static constexpr float INVDH2 = 1.0f / (10.0f * 10.0f);

#define KSTEPS 16                 // fused steps per phase
#define TILE   32                 // interior tile edge
#define RPT    8                  // ext rows per thread (4 float2 pairs)
#define NPAIRS 4                  // RPT/2
#define NWAVES 8
#define BLOCK  512
#define NWG    (NSHOTS * 64)      // 256 WGs, one per CU (co-resident)
#define NPHASE (NT / KSTEPS)      // 32
#define FSTR   32                 // dwords between wave flags (128 B)

typedef float v2f __attribute__((ext_vector_type(2)));
typedef unsigned long long ull;

// lane i <- lane i-1 (left x-neighbor); OOB lane 0 reads 0 (bound_ctrl=1)
__device__ __forceinline__ float nbr_left(float v) {
  return __int_as_float(__builtin_amdgcn_update_dpp(
      0, __float_as_int(v), 0x138 /*WAVE_SHR1*/, 0xf, 0xf, true));
}
// lane i <- lane i+1 (right x-neighbor); OOB lane 63 reads 0
__device__ __forceinline__ float nbr_right(float v) {
  return __int_as_float(__builtin_amdgcn_update_dpp(
      0, __float_as_int(v), 0x130 /*WAVE_SHL1*/, 0xf, 0xf, true));
}

// LLC-coherent (cross-XCD) 8B access: agent-scope relaxed -> sc0 sc1.
__device__ __forceinline__ ull pload(const ull* p) {
  return __hip_atomic_load(p, __ATOMIC_RELAXED, __HIP_MEMORY_SCOPE_AGENT);
}
__device__ __forceinline__ void pstore(ull* p, ull v) {
  __hip_atomic_store(p, v, __ATOMIC_RELAXED, __HIP_MEMORY_SCOPE_AGENT);
}

// pack (cur, prev) into one self-tagged 8B word: low 2 bits of prev's
// mantissa carry the phase tag (<= 3 ulp perturbation of halo prev only)
__device__ __forceinline__ ull pack_w(float cur, float prev, unsigned tg) {
  const unsigned hi = (__float_as_uint(prev) & ~3u) | tg;
  return ((ull)hi << 32) | (ull)__float_as_uint(cur);
}
__device__ __forceinline__ float w_cur(ull w) {
  return __uint_as_float((unsigned)w);
}
__device__ __forceinline__ float w_prev(ull w) {
  return __uint_as_float(((unsigned)(w >> 32)) & ~3u);
}
// per-buffer tag cycles 1,2,3 (phase q uses buffer q&1): never 0 (= memset)
__device__ __forceinline__ unsigned tag_of(int q) {
  return ((unsigned)(q >> 1) % 3u) + 1u;
}

// LDS wave-flag ops (workgroup scope)
__device__ __forceinline__ int lflag(const int* p) {
  return __hip_atomic_load(p, __ATOMIC_ACQUIRE, __HIP_MEMORY_SCOPE_WORKGROUP);
}
__device__ __forceinline__ void sflag(int* p, int v) {
  __hip_atomic_store(p, v, __ATOMIC_RELEASE, __HIP_MEMORY_SCOPE_WORKGROUP);
}

__global__ __launch_bounds__(BLOCK, 2) void wave_pk(
    ull* __restrict__ gA, ull* __restrict__ gB,         // tagged (cur,prev) buffers
    const float* __restrict__ vp, const float* __restrict__ xwav,
    const int* __restrict__ src_z, const int* __restrict__ src_x,
    const int* __restrict__ rec_z, const int* __restrict__ rec_x,
    float* __restrict__ out)                            // [NSHOTS*NT*NRECS]
{
  const int bid  = blockIdx.x;
  const int s    = bid >> 6;
  const int tz   = (bid >> 3) & 7;
  const int tx   = bid & 7;
  const int tid  = threadIdx.x;
  const int w    = tid >> 6;
  const int lane = tid & 63;

  const int gz0 = tz * TILE - KSTEPS;
  const int gx0 = tx * TILE - KSTEPS;
  const int gx  = gx0 + lane;
  const int zb  = w * RPT;

  __shared__ float hT[2][NWAVES][64];   // per-wave top row, slot = step&1
  __shared__ float hB[2][NWAVES][64];   // per-wave bottom row
  __shared__ int   wfl[NWAVES * FSTR];  // per-wave monotone step counters
  __shared__ int   lzS[NRECS], lxS[NRECS];

  // receiver table -> LDS
  if (tid < NRECS) {
    lzS[tid] = rec_z[s * NRECS + tid] - tz * TILE;
    lxS[tid] = rec_x[s * NRECS + tid] - tx * TILE;
  }
  // initial state (p0 = 0) published in both slots; flags = 0
  hT[0][w][lane] = 0.0f; hB[0][w][lane] = 0.0f;
  hT[1][w][lane] = 0.0f; hB[1][w][lane] = 0.0f;
  if (lane == 0)
    __hip_atomic_store(&wfl[w * FSTR], 0, __ATOMIC_RELAXED,
                       __HIP_MEMORY_SCOPE_WORKGROUP);

  // interior (writeback) threads: ext rows 16..47, ext lanes 16..47
  const bool wbT = (w >= 2 && w < 6) && (lane >= KSTEPS && lane < KSTEPS + TILE);

  // phase-invariant per-row addresses/validity; c2 and d2=2-4c2 packed
  const bool xok = (unsigned)gx < (unsigned)NX;
  int   offRow[RPT];
  v2f a2[NPAIRS], b2[NPAIRS], c22[NPAIRS], d22[NPAIRS];
  unsigned okMask = 0;
  #pragma unroll
  for (int p = 0; p < NPAIRS; ++p) {
    #pragma unroll
    for (int h = 0; h < 2; ++h) {
      const int i  = 2 * p + h;
      const int gz = gz0 + zb + i;
      const bool ok = xok && ((unsigned)gz < (unsigned)NZ);
      if (ok) okMask |= 1u << i;
      offRow[i] = ok ? ((s * NZ + gz) * NX + gx) : 0;
      float v = ok ? vp[gz * NX + gx] : 0.0f;
      v *= DTf;
      const float c2 = v * v * INVDH2;
      if (h == 0) { c22[p].x = c2; d22[p].x = 2.0f - 4.0f * c2; }
      else        { c22[p].y = c2; d22[p].y = 2.0f - 4.0f * c2; }
    }
    a2[p] = (v2f)(0.0f); b2[p] = (v2f)(0.0f);
  }

  // source mask; hasSrcW is wave-uniform (source inside my wave's rows)
  const int slz = src_z[s] - gz0;
  const int slx = src_x[s] - gx0;
  const bool hasSrcW = ((unsigned)slx < 64u) &&
                       ((unsigned)(slz - zb) < (unsigned)RPT);
  const bool srcMine = hasSrcW && (slx == lane);
  const int  srcI = slz - zb;
  v2f srcM2[NPAIRS];
  #pragma unroll
  for (int p = 0; p < NPAIRS; ++p) {
    srcM2[p].x = (srcMine && srcI == 2 * p)     ? 1.0f : 0.0f;
    srcM2[p].y = (srcMine && srcI == 2 * p + 1) ? 1.0f : 0.0f;
  }

  __syncthreads();   // flags + rec table + initial halo rows visible

  // receiver ownership: owner = wbT thread holding the cell; 2 packed fast
  // slots + overflow bitmask (row = ext-row & 7 within the owning wave)
  unsigned e0 = 0, e1 = 0, rB0 = 0, rB1 = 0, rB2 = 0, rB3 = 0;
  if (wbT) {
    int cnt = 0;
    #pragma unroll 1
    for (int r = 0; r < NRECS; ++r) {
      const int er = lzS[r], ex = lxS[r];
      if ((unsigned)er < (unsigned)TILE && (unsigned)ex < (unsigned)TILE) {
        const int extz = er + KSTEPS;
        if ((extz >> 3) == w && ex + KSTEPS == lane) {
          const unsigned e = 0x8000u | ((unsigned)(extz & 7) << 8) | (unsigned)r;
          if (cnt == 0) e0 = e;
          else if (cnt == 1) e1 = e;
          else {
            if (r < 32)      rB0 |= 1u << r;
            else if (r < 64) rB1 |= 1u << (r - 32);
            else if (r < 96) rB2 |= 1u << (r - 64);
            else             rB3 |= 1u << (r - 96);
          }
          ++cnt;
        }
      }
    }
  }
  const bool hasOvf = (rB0 | rB1 | rB2 | rB3) != 0;

  float amp[KSTEPS];

  // value of my-wave row (0..7) from nxt pairs
  auto selRow = [](const v2f (&n)[NPAIRS], int row) -> float {
    const v2f pA = (row & 2) ? n[1] : n[0];
    const v2f pB = (row & 2) ? n[3] : n[2];
    const v2f pp = (row & 4) ? pB : pA;
    return (row & 1) ? pp.y : pp.x;
  };

  // one step with pairwise wave relay sync (no WG barrier)
  auto do_step = [&](v2f (&cur)[NPAIRS], v2f (&nxt)[NPAIRS], int tau, int t0) {
    const int tg = t0 + tau + 1;        // global monotone step counter
    // wait only for z-adjacent waves' step tg-1 publication
    if (w > 0)
      while (lflag(&wfl[(w - 1) * FSTR]) < tg - 1) {}
    if (w < NWAVES - 1)
      while (lflag(&wfl[(w + 1) * FSTR]) < tg - 1) {}
    const int rs = (tg - 1) & 1;
    const float up0 = (w > 0)          ? hB[rs][w - 1][lane] : 0.0f;
    const float dn7 = (w < NWAVES - 1) ? hT[rs][w + 1][lane] : 0.0f;
    #pragma unroll
    for (int p = 0; p < NPAIRS; ++p) {
      const float cx = cur[p].x, cy = cur[p].y;
      const float upx = (p == 0)          ? up0 : cur[p - 1].y;
      const float dny = (p == NPAIRS - 1) ? dn7 : cur[p + 1].x;
      v2f ud, lr;
      ud.x = upx + cy;
      ud.y = cx + dny;
      lr.x = nbr_left(cx) + nbr_right(cx);
      lr.y = nbr_left(cy) + nbr_right(cy);
      const v2f sum = ud + lr;
      v2f t = __builtin_elementwise_fma(c22[p], sum, -nxt[p]);
      t = __builtin_elementwise_fma(d22[p], cur[p], t);
      nxt[p] = t;
    }
    if (hasSrcW) {                       // wave-uniform; few waves pay
      const v2f av = { amp[tau], amp[tau] };
      #pragma unroll
      for (int p = 0; p < NPAIRS; ++p)
        nxt[p] = __builtin_elementwise_fma(srcM2[p], av, nxt[p]);
    }
    if (tau != KSTEPS - 1) {             // last phase step: rows eroded ->
      const int ws2 = tg & 1;            // re-published after reload instead
      hT[ws2][w][lane] = nxt[0].x;
      hB[ws2][w][lane] = nxt[NPAIRS - 1].y;
      if (lane == 0) sflag(&wfl[w * FSTR], tg);
    }
    // receiver stores: owner thread has the value in registers
    const int t = t0 + tau;
    if (e0 & 0x8000u)
      out[(s * NT + t) * NRECS + (e0 & 127u)] = selRow(nxt, (e0 >> 8) & 7);
    if (e1 & 0x8000u)
      out[(s * NT + t) * NRECS + (e1 & 127u)] = selRow(nxt, (e1 >> 8) & 7);
    if (hasOvf) {                        // >2 recs on one thread (rare)
      #pragma unroll
      for (int wd = 0; wd < 4; ++wd) {
        unsigned m = (wd == 0) ? rB0 : (wd == 1) ? rB1 : (wd == 2) ? rB2 : rB3;
        while (m) {
          const int b = __builtin_ctz(m); m &= m - 1;
          const int r = wd * 32 + b;
          out[(s * NT + t) * NRECS + r] = selRow(nxt, (lzS[r] + KSTEPS) & 7);
        }
      }
    }
  };

  #pragma unroll 1
  for (int ph = 0; ph < NPHASE; ++ph) {
    const int t0 = ph * KSTEPS;

    if (hasSrcW) {      // wavelet only needed by source-carrying waves
      const float4* xw4 = (const float4*)(xwav + s * NT + t0);
      #pragma unroll
      for (int q = 0; q < KSTEPS / 4; ++q) {
        const float4 v = xw4[q];
        amp[4 * q + 0] = (v.x * DTf) * DTf;
        amp[4 * q + 1] = (v.y * DTf) * DTf;
        amp[4 * q + 2] = (v.z * DTf) * DTf;
        amp[4 * q + 3] = (v.w * DTf) * DTf;
      }
    }

    if (ph > 0) {
      if (!wbT) {
        // fused poll+reload on self-tagged data words (R6-proven): tag match
        // certifies producer's writeback AND (program order + relay chain)
        // its prior reload -> covers data-dep and anti-dep.
        const ull* gR = (ph & 1) ? gA : gB;
        const unsigned tg = tag_of(ph - 1);
        ull vw[RPT];
        unsigned need = okMask;
        while (need) {
          ull t[RPT];
          #pragma unroll
          for (int i = 0; i < RPT; ++i)
            if (need & (1u << i)) t[i] = pload(gR + offRow[i]);
          #pragma unroll
          for (int i = 0; i < RPT; ++i)
            if ((need & (1u << i)) && (((unsigned)(t[i] >> 32)) & 3u) == tg) {
              vw[i] = t[i];
              need &= ~(1u << i);
            }
          if (need) __builtin_amdgcn_s_sleep(1);
        }
        #pragma unroll
        for (int i = 0; i < RPT; ++i) {
          const bool ok = (okMask >> i) & 1;
          const float cv = ok ? w_cur(vw[i])  : 0.0f;
          const float pv = ok ? w_prev(vw[i]) : 0.0f;
          if (i & 1) { a2[i >> 1].y = cv; b2[i >> 1].y = pv; }
          else       { a2[i >> 1].x = cv; b2[i >> 1].x = pv; }
        }
      }
      // post-reload publish of corrected p(t0) rows; slot t0&1 == 0.
      // Safe WAR: my step-t0 compute already required w+-1 flags >= t0-1,
      // so their reads of this slot's old content are done.
      hT[0][w][lane] = a2[0].x;
      hB[0][w][lane] = a2[NPAIRS - 1].y;
      if (lane == 0) sflag(&wfl[w * FSTR], t0);
    }

    #pragma unroll
    for (int h = 0; h < KSTEPS / 2; ++h) {
      do_step(a2, b2, 2 * h,     t0);
      do_step(b2, a2, 2 * h + 1, t0);
    }

    if (ph != NPHASE - 1 && wbT) {
      // tagged writeback IS the inter-tile handshake (no drain, no flag)
      ull* gW = (ph & 1) ? gB : gA;
      const unsigned tgw = tag_of(ph);
      #pragma unroll
      for (int p = 0; p < NPAIRS; ++p) {
        pstore(gW + offRow[2 * p],     pack_w(a2[p].x, b2[p].x, tgw));
        pstore(gW + offRow[2 * p + 1], pack_w(a2[p].y, b2[p].y, tgw));
      }
    }
  }
}

extern "C" void kernel_launch(void* const* d_in, const int* in_sizes, int n_in,
                              void* d_out, int out_size, void* d_ws, size_t ws_size,
                              hipStream_t stream) {
  const float* x     = (const float*)d_in[0];
  const float* vp    = (const float*)d_in[1];
  const int*   src_z = (const int*)d_in[2];
  const int*   src_x = (const int*)d_in[3];
  const int*   rec_z = (const int*)d_in[4];
  const int*   rec_x = (const int*)d_in[5];
  float* out = (float*)d_out;

  const size_t F = (size_t)NSHOTS * NZ * NX;
  ull* gA = (ull*)d_ws;                 // tagged (cur,prev), F words
  ull* gB = gA + F;                     // F words

  // zero both buffers: tag bits 0 never match any valid tag (1..3)
  hipMemsetAsync(gA, 0, 2 * F * sizeof(ull), stream);

  wave_pk<<<dim3(NWG), dim3(BLOCK), 0, stream>>>(
      gA, gB, vp, x, src_z, src_x, rec_z, rec_x, out);
}